// Round 1
// baseline (256.280 us; speedup 1.0000x reference)
//
#include <hip/hip_runtime.h>

constexpr int N_VARS   = 2048;
constexpr int NODES    = 4096;
constexpr int N_LAYERS = 8;
constexpr int BATCH    = 8192;
constexpr int THREADS  = 512;               // 8 waves/block; 3 blocks/CU -> 24 waves/CU
constexpr int RPB      = 2;                 // batch rows per block
constexpr int NPT      = NODES / THREADS;   // 8 nodes/thread/layer

// ---- bf16x2 word = row0 bf16 (low 16) | row1 bf16 (high 16) ----
__device__ __forceinline__ float bflo(unsigned w) { return __uint_as_float(w << 16); }
__device__ __forceinline__ float bfhi(unsigned w) { return __uint_as_float(w & 0xffff0000u); }

// Single-instruction RNE pack of 2 f32 -> bf16x2 (replaces 11-op manual RNE).
__device__ __forceinline__ unsigned bfpack(float lo, float hi) {
  unsigned r;
  asm("v_cvt_pk_bf16_f32 %0, %1, %2" : "=v"(r) : "v"(lo), "v"(hi));
  return r;
}

// MODE: 0 = pre-packed ushort4 BYTE OFFSETS (d_ws), 1 = raw int32, 2 = raw int64.
// SHIFT: element->byte scale for the raw paths (3 for float2/A, 2 for bf16x2/B).
template <int MODE, int SHIFT>
__device__ __forceinline__ ushort4 get_off(const void* p, int n) {
  if (MODE == 0) return ((const ushort4*)p)[n];   // already byte-scaled at pack time
  if (MODE == 1) {
    int4 c = ((const int4*)p)[n];
    return make_ushort4((unsigned short)(c.x << SHIFT), (unsigned short)(c.y << SHIFT),
                        (unsigned short)(c.z << SHIFT), (unsigned short)(c.w << SHIFT));
  }
  const int* q = (const int*)p + (size_t)n * 8;
  return make_ushort4((unsigned short)(q[0] << SHIFT), (unsigned short)(q[2] << SHIFT),
                      (unsigned short)(q[4] << SHIFT), (unsigned short)(q[6] << SHIFT));
}
template <int MODE> __device__ __forceinline__ size_t layer_bytes() {
  return MODE == 0 ? (size_t)NODES * 8 : MODE == 1 ? (size_t)NODES * 16
                                                   : (size_t)NODES * 32;
}

// Prod layer: gather fp32 float2 from A, multiply in fp32, store bf16x2 to B.
template <int MODE>
__device__ __forceinline__ void prod_pass(const float2* A, unsigned* B,
                                          const void* idx, int t) {
  const char* Ab = (const char*)A;
#pragma unroll
  for (int i = 0; i < NPT; ++i) {
    const int n = t + i * THREADS;
    ushort4 c = get_off<MODE, 3>(idx, n);
    float2 a = *(const float2*)(Ab + c.x);
    float2 b = *(const float2*)(Ab + c.y);
    float2 d = *(const float2*)(Ab + c.z);
    float2 e = *(const float2*)(Ab + c.w);
    B[n] = bfpack(a.x * b.x * d.x * e.x, a.y * b.y * d.y * e.y);
  }
}

// Sum layer: gather bf16x2 from B, add in fp32, store fp32 float2 to A.
template <int MODE>
__device__ __forceinline__ void sum_pass(const unsigned* B, float2* A,
                                         const void* idx, int t) {
  const char* Bb = (const char*)B;
#pragma unroll
  for (int i = 0; i < NPT; ++i) {
    const int n = t + i * THREADS;
    ushort4 c = get_off<MODE, 2>(idx, n);
    unsigned a = *(const unsigned*)(Bb + c.x);
    unsigned b = *(const unsigned*)(Bb + c.y);
    unsigned d = *(const unsigned*)(Bb + c.z);
    unsigned e = *(const unsigned*)(Bb + c.w);
    A[n] = make_float2(bflo(a) + bflo(b) + bflo(d) + bflo(e),
                       bfhi(a) + bfhi(b) + bfhi(d) + bfhi(e));
  }
}

template <int MODE>
__device__ __forceinline__ void spn_body(const float* __restrict__ x,
                                         const unsigned char* __restrict__ marg,
                                         const void* __restrict__ idx,
                                         float* __restrict__ out,
                                         float2* A,          // 4096 fp32x2 = 32 KB
                                         unsigned* B) {      // 4096 bf16x2 = 16 KB
  const int t = threadIdx.x;
  const int row0 = blockIdx.x * RPB;
  const float* x0 = x + (size_t)row0 * N_VARS;
  const float* x1 = x0 + N_VARS;

  // Stage leaves in fp32 (leaf rounding would be prod-amplified -> keep exact).
#pragma unroll
  for (int i = 0; i < N_VARS / THREADS; ++i) {  // 4 iterations
    const int j = t + i * THREADS;
    const float a = x0[j], b = x1[j];
    const bool m = marg[j] != 0;
    A[j]          = make_float2(m ? 1.f : a,       m ? 1.f : b);
    A[N_VARS + j] = make_float2(m ? 1.f : 1.f - a, m ? 1.f : 1.f - b);
  }

  const char* ib = (const char*)idx;
  const size_t LB = layer_bytes<MODE>();
  __syncthreads();
  prod_pass<MODE>(A, B, ib + 0 * LB, t); __syncthreads();   // L0
  sum_pass <MODE>(B, A, ib + 1 * LB, t); __syncthreads();   // L1 (overwrites leaves)
  prod_pass<MODE>(A, B, ib + 2 * LB, t); __syncthreads();   // L2
  sum_pass <MODE>(B, A, ib + 3 * LB, t); __syncthreads();   // L3
  prod_pass<MODE>(A, B, ib + 4 * LB, t); __syncthreads();   // L4
  sum_pass <MODE>(B, A, ib + 5 * LB, t); __syncthreads();   // L5
  prod_pass<MODE>(A, B, ib + 6 * LB, t); __syncthreads();   // L6

  // L7 (sum) fused into node reduction: gather bf16 from B, accumulate fp32.
  float s0 = 0.f, s1 = 0.f;
  {
    const void* L7 = ib + 7 * LB;
    const char* Bb = (const char*)B;
#pragma unroll
    for (int i = 0; i < NPT; ++i) {
      const int n = t + i * THREADS;
      ushort4 c = get_off<MODE, 2>(L7, n);
      unsigned a = *(const unsigned*)(Bb + c.x);
      unsigned b = *(const unsigned*)(Bb + c.y);
      unsigned d = *(const unsigned*)(Bb + c.z);
      unsigned e = *(const unsigned*)(Bb + c.w);
      s0 += bflo(a) + bflo(b) + bflo(d) + bflo(e);
      s1 += bfhi(a) + bfhi(b) + bfhi(d) + bfhi(e);
    }
  }
#pragma unroll
  for (int off = 32; off > 0; off >>= 1) {
    s0 += __shfl_down(s0, off);
    s1 += __shfl_down(s1, off);
  }
  if ((t & 63) == 0) A[t >> 6] = make_float2(s0, s1);  // A free after last sync
  __syncthreads();
  if (t == 0) {
    float2 tot = A[0];
#pragma unroll
    for (int w = 1; w < THREADS / 64; ++w) { tot.x += A[w].x; tot.y += A[w].y; }
    out[row0]     = tot.x;
    out[row0 + 1] = tot.y;
  }
}

__global__ __launch_bounds__(THREADS) void spn_packed(
    const float* __restrict__ x, const unsigned char* __restrict__ marg,
    const ushort4* __restrict__ idx, float* __restrict__ out) {
  __shared__ float2   A[NODES];   // 32 KB
  __shared__ unsigned B[NODES];   // 16 KB  -> 48 KB total, 3 blocks/CU
  spn_body<0>(x, marg, idx, out, A, B);
}

__global__ __launch_bounds__(THREADS) void spn_raw(
    const float* __restrict__ x, const unsigned char* __restrict__ marg,
    const int* __restrict__ cidx, float* __restrict__ out) {
  __shared__ float2   A[NODES];
  __shared__ unsigned B[NODES];
  int acc = 0;  // int64 storage => odd words all zero (indices < 4096)
#pragma unroll
  for (int k = 0; k < 8; ++k) acc |= cidx[2 * k + 1];
  if (acc == 0) spn_body<2>(x, marg, cidx, out, A, B);
  else          spn_body<1>(x, marg, cidx, out, A, B);
}

// -----------------------------------------------------------------------------
// Bank-aware index pack. The gather pattern is STATIC (child_idx fixed) and
// sum/prod are commutative, so we choose which child lands in which gather
// SLOT. A wave-instruction j gathers slot j of an aligned 64-node group:
// balancing slot-j addresses across LDS banks within each group kills the
// random-gather conflicts (A: 16 bank-pair bins, B: 32 bank bins).
// One thread per 64-node group; greedy over all 24 child permutations with a
// squared-load cost (approximates minimizing max bank load).
// Output is byte-prescaled: even layers gather A (float2, <<3), odd gather B
// (bf16x2, <<2) -- also removes 4 address shifts/node from the hot kernel.
// -----------------------------------------------------------------------------
__global__ __launch_bounds__(64) void pack_idx(const int* __restrict__ cidx,
                                               ushort4* __restrict__ out) {
  __shared__ unsigned short cnt[64][4][32];   // per-thread [slot][bank] loads, 16 KB
  const int tid   = threadIdx.x;              // 0..63
  const int gid   = blockIdx.x * 64 + tid;    // 0..511
  const int layer = gid >> 6;                 // 8 layers
  const int group = gid & 63;                 // 64 groups of 64 nodes
  const int shift = (layer & 1) ? 2 : 3;
  const int mask  = (layer & 1) ? 31 : 15;    // B: bank (4B); A: bank-pair (8B)

  int acc = 0;                                // int64 vs int32 detection
#pragma unroll
  for (int k = 0; k < 8; ++k) acc |= cidx[2 * k + 1];
  const bool is64 = (acc == 0);

#pragma unroll
  for (int s = 0; s < 4; ++s)
#pragma unroll
    for (int b = 0; b < 32; ++b) cnt[tid][s][b] = 0;

  constexpr unsigned char P24[24][4] = {      // identity first: ties keep ref order
      {0,1,2,3},{0,1,3,2},{0,2,1,3},{0,2,3,1},{0,3,1,2},{0,3,2,1},
      {1,0,2,3},{1,0,3,2},{1,2,0,3},{1,2,3,0},{1,3,0,2},{1,3,2,0},
      {2,0,1,3},{2,0,3,1},{2,1,0,3},{2,1,3,0},{2,3,0,1},{2,3,1,0},
      {3,0,1,2},{3,0,2,1},{3,1,0,2},{3,1,2,0},{3,2,0,1},{3,2,1,0}};

  const int n0 = group * 64;
  for (int k = 0; k < 64; ++k) {
    const int node = n0 + k;
    int cv[4];
    if (is64) {
      const int* q = cidx + (size_t)(layer * NODES + node) * 8;
      cv[0] = q[0]; cv[1] = q[2]; cv[2] = q[4]; cv[3] = q[6];
    } else {
      int4 v = ((const int4*)cidx)[layer * NODES + node];
      cv[0] = v.x; cv[1] = v.y; cv[2] = v.z; cv[3] = v.w;
    }
    int bn[4];
#pragma unroll
    for (int j = 0; j < 4; ++j) bn[j] = cv[j] & mask;
    int m2[4][4];                              // m2[s][j] = cnt[s][bin_j]^2 (registers)
#pragma unroll
    for (int s = 0; s < 4; ++s)
#pragma unroll
      for (int j = 0; j < 4; ++j) {
        const int v = cnt[tid][s][bn[j]];
        m2[s][j] = v * v;
      }
    int bestc = 0x7fffffff;
    int o0 = cv[0], o1 = cv[1], o2 = cv[2], o3 = cv[3];
    int b0 = bn[0], b1 = bn[1], b2 = bn[2], b3 = bn[3];
#pragma unroll
    for (int p = 0; p < 24; ++p) {
      const int j0 = P24[p][0], j1 = P24[p][1], j2 = P24[p][2], j3 = P24[p][3];
      const int cost = m2[0][j0] + m2[1][j1] + m2[2][j2] + m2[3][j3];
      if (cost < bestc) {
        bestc = cost;
        o0 = cv[j0]; o1 = cv[j1]; o2 = cv[j2]; o3 = cv[j3];
        b0 = bn[j0]; b1 = bn[j1]; b2 = bn[j2]; b3 = bn[j3];
      }
    }
    cnt[tid][0][b0]++; cnt[tid][1][b1]++; cnt[tid][2][b2]++; cnt[tid][3][b3]++;
    out[layer * NODES + node] =
        make_ushort4((unsigned short)(o0 << shift), (unsigned short)(o1 << shift),
                     (unsigned short)(o2 << shift), (unsigned short)(o3 << shift));
  }
}

extern "C" void kernel_launch(void* const* d_in, const int* in_sizes, int n_in,
                              void* d_out, int out_size, void* d_ws, size_t ws_size,
                              hipStream_t stream) {
  const float* x          = (const float*)d_in[0];
  const unsigned char* mg = (const unsigned char*)d_in[1];
  const int* cidx         = (const int*)d_in[2];
  float* out              = (float*)d_out;

  const size_t need = (size_t)N_LAYERS * NODES * sizeof(ushort4);  // 256 KB
  if (ws_size >= need) {
    ushort4* packed = (ushort4*)d_ws;
    hipLaunchKernelGGL(pack_idx, dim3(8), dim3(64), 0, stream, cidx, packed);
    hipLaunchKernelGGL(spn_packed, dim3(BATCH / RPB), dim3(THREADS), 0, stream,
                       x, mg, packed, out);
  } else {
    hipLaunchKernelGGL(spn_raw, dim3(BATCH / RPB), dim3(THREADS), 0, stream,
                       x, mg, cidx, out);
  }
}